// Round 3
// baseline (3090.952 us; speedup 1.0000x reference)
//
#include <hip/hip_runtime.h>
#include <hip/hip_bf16.h>

#define HW 65536
#define BATCH 4
#define NPIX (BATCH*HW)   // 262144 pixels

typedef unsigned short u16;
typedef unsigned int   u32;

__device__ __forceinline__ float b2f(u16 u){
    u32 i = ((u32)u) << 16; float f; __builtin_memcpy(&f, &i, 4); return f;
}
__device__ __forceinline__ u16 f2b(float f){
    __hip_bfloat16 h = __float2bfloat16(f); u16 u; __builtin_memcpy(&u, &h, 2); return u;
}
__device__ __forceinline__ float ldv(const float* p){ return *p; }
__device__ __forceinline__ float ldv(const u16*  p){ return b2f(*p); }

// ---------------- per-pixel LayerNorm over 64 channels (f32 in -> bf16 out) ----------------
__global__ __launch_bounds__(256) void ln_kernel(const float* __restrict__ x,
                                                 const float* __restrict__ w,
                                                 const float* __restrict__ bsh,
                                                 u16* __restrict__ out){
    int b = blockIdx.x >> 8;
    int n = ((blockIdx.x & 255) << 8) | threadIdx.x;
    const float* px = x  + (size_t)b*64*HW + n;
    u16*         po = out + (size_t)b*64*HW + n;
    float v[64]; float mu = 0.f;
    #pragma unroll
    for (int c = 0; c < 64; c++){ v[c] = px[(size_t)c*HW]; mu += v[c]; }
    mu *= (1.f/64.f);
    float var = 0.f;
    #pragma unroll
    for (int c = 0; c < 64; c++){ float d = v[c]-mu; var += d*d; }
    var *= (1.f/64.f);
    float inv = rsqrtf(var + 1e-5f);
    #pragma unroll
    for (int c = 0; c < 64; c++)
        po[(size_t)c*HW] = f2b((v[c]-mu)*inv*w[c] + bsh[c]);
}

// ---------------- generic 1x1 conv (per-pixel matvec, SGPR weights) ----------------
template<typename TI, int CIN, int COUT, bool LRELU, bool BIAS>
__global__ __launch_bounds__(256) void conv1x1_kernel(const TI* __restrict__ in,
                                                      const float* __restrict__ w,
                                                      const float* __restrict__ bias,
                                                      u16* __restrict__ out){
    int b = blockIdx.x >> 8;
    int n = ((blockIdx.x & 255) << 8) | threadIdx.x;
    const TI* pin = in + (size_t)b*CIN*HW + n;
    float v[CIN];
    #pragma unroll
    for (int c = 0; c < CIN; c++) v[c] = ldv(pin + (size_t)c*HW);
    u16* po = out + (size_t)b*COUT*HW + n;
    #pragma unroll 2
    for (int o = 0; o < COUT; o++){
        float acc = BIAS ? bias[o] : 0.f;
        const float* wr = w + o*CIN;
        #pragma unroll
        for (int c = 0; c < CIN; c++) acc = fmaf(wr[c], v[c], acc);
        if (LRELU) acc = (acc > 0.f) ? acc : 0.1f*acc;
        po[(size_t)o*HW] = f2b(acc);
    }
}

// ---------------- depthwise 3x3, pad 1 (bf16 planes) ----------------
__global__ __launch_bounds__(256) void dwconv_kernel(const u16* __restrict__ in,
                                                     const float* __restrict__ w,
                                                     u16* __restrict__ out, int C){
    int bc = blockIdx.x >> 8;                       // (b*C + c), wave-uniform
    int n  = ((blockIdx.x & 255) << 8) | threadIdx.x;
    int c  = bc - (bc / C) * C;
    int h = n >> 8, col = n & 255;
    const float* wc = w + c*9;
    const u16* p = in + (size_t)bc*HW;
    float acc = 0.f;
    #pragma unroll
    for (int di = -1; di <= 1; di++){
        int hh = h + di;
        if ((unsigned)hh < 256u){
            #pragma unroll
            for (int dj = -1; dj <= 1; dj++){
                int ww = col + dj;
                if ((unsigned)ww < 256u)
                    acc = fmaf(wc[(di+1)*3 + (dj+1)], b2f(p[hh*256 + ww]), acc);
            }
        }
    }
    out[(size_t)bc*HW + n] = f2b(acc);
}

// ---------------- v = v*(s+1)+t, in place on the v half of kv ----------------
__global__ __launch_bounds__(256) void vmod_kernel(u16* __restrict__ kv,
                                                   const u16* __restrict__ s,
                                                   const u16* __restrict__ t){
    int idx = blockIdx.x*256 + threadIdx.x;         // over B*64*HW
    int b = blockIdx.x >> 14;                       // 64*HW elems per batch
    int r = idx & ((1<<22)-1);
    u16* pv = kv + (size_t)b*128*HW + (size_t)64*HW + r;
    float v = b2f(*pv), sv = b2f(s[idx]), tv = b2f(t[idx]);
    *pv = f2b(v*(sv+1.f)+tv);
}

// ---------------- channel-attention stats: Gram + norms + softmax ----------------
__global__ __launch_bounds__(256) void attn_kernel(const u16* __restrict__ q,
                                                   const u16* __restrict__ kv,
                                                   const float* __restrict__ temp,
                                                   float* __restrict__ attn){
    int b = blockIdx.x >> 3, h = blockIdx.x & 7;
    const u16* qp = q  + ((size_t)b*64  + h*8)*HW;
    const u16* kp = kv + ((size_t)b*128 + h*8)*HW;
    float acc[80];
    #pragma unroll
    for (int i = 0; i < 80; i++) acc[i] = 0.f;
    for (int n = threadIdx.x; n < HW; n += 256){
        float qv[8], kw[8];
        #pragma unroll
        for (int i = 0; i < 8; i++){
            qv[i] = b2f(qp[(size_t)i*HW + n]);
            kw[i] = b2f(kp[(size_t)i*HW + n]);
        }
        #pragma unroll
        for (int i = 0; i < 8; i++){
            acc[64+i] = fmaf(qv[i], qv[i], acc[64+i]);
            acc[72+i] = fmaf(kw[i], kw[i], acc[72+i]);
            #pragma unroll
            for (int j = 0; j < 8; j++) acc[i*8+j] = fmaf(qv[i], kw[j], acc[i*8+j]);
        }
    }
    __shared__ float sred[4*80];
    __shared__ float fin[80];
    int lane = threadIdx.x & 63, wv = threadIdx.x >> 6;
    #pragma unroll
    for (int t = 0; t < 80; t++){
        float r = acc[t];
        for (int o = 32; o > 0; o >>= 1) r += __shfl_down(r, o, 64);
        if (lane == 0) sred[wv*80 + t] = r;
    }
    __syncthreads();
    if (threadIdx.x < 80)
        fin[threadIdx.x] = sred[threadIdx.x] + sred[80+threadIdx.x]
                         + sred[160+threadIdx.x] + sred[240+threadIdx.x];
    __syncthreads();   // fin[64..79] written by wave 1; readers are wave 0
    if (threadIdx.x < 8){
        int i = threadIdx.x;
        float iq = 1.f / fmaxf(sqrtf(fin[64+i]), 1e-12f);
        float tv = temp[h];
        float row[8]; float m = -1e30f;
        #pragma unroll
        for (int j = 0; j < 8; j++){
            float ik = 1.f / fmaxf(sqrtf(fin[72+j]), 1e-12f);
            row[j] = fin[i*8+j]*iq*ik*tv;
            m = fmaxf(m, row[j]);
        }
        float ssum = 0.f;
        #pragma unroll
        for (int j = 0; j < 8; j++){ row[j] = expf(row[j]-m); ssum += row[j]; }
        float rs = 1.f/ssum;
        #pragma unroll
        for (int j = 0; j < 8; j++)
            attn[((b*8+h)*8+i)*8+j] = row[j]*rs;
    }
}

// ---------------- fused attn-apply + po conv1x1 + residual (f32 resid/out) ----------------
__global__ __launch_bounds__(256) void final_kernel(const u16* __restrict__ kv,
                                                    const float* __restrict__ attn,
                                                    const float* __restrict__ po,
                                                    const float* __restrict__ resid,
                                                    float* __restrict__ out){
    int b = blockIdx.x >> 8;
    int n = ((blockIdx.x & 255) << 8) | threadIdx.x;
    const u16* vp = kv + ((size_t)b*128 + 64)*HW + n;
    float v[64];
    #pragma unroll
    for (int c = 0; c < 64; c++) v[c] = b2f(vp[(size_t)c*HW]);
    float ao[64];
    const float* att = attn + b*512;
    #pragma unroll
    for (int h = 0; h < 8; h++){
        #pragma unroll
        for (int i = 0; i < 8; i++){
            float a = 0.f;
            #pragma unroll
            for (int j = 0; j < 8; j++) a = fmaf(att[(h*8+i)*8+j], v[h*8+j], a);
            ao[h*8+i] = a;
        }
    }
    const float* rp = resid + (size_t)b*64*HW + n;
    float*       op = out   + (size_t)b*64*HW + n;
    #pragma unroll 2
    for (int o = 0; o < 64; o++){
        float acc = rp[(size_t)o*HW];
        const float* wr = po + o*64;
        #pragma unroll
        for (int c = 0; c < 64; c++) acc = fmaf(wr[c], ao[c], acc);
        op[(size_t)o*HW] = acc;
    }
}

extern "C" void kernel_launch(void* const* d_in, const int* in_sizes, int n_in,
                              void* d_out, int out_size, void* d_ws, size_t ws_size,
                              hipStream_t stream){
    const float* x    = (const float*)d_in[0];
    const float* y    = (const float*)d_in[1];
    const float* ln_w = (const float*)d_in[2];
    const float* ln_b = (const float*)d_in[3];
    const float* temp = (const float*)d_in[4];
    const float* kv_w[2]   = {(const float*)d_in[5],  (const float*)d_in[10]};
    const float* kvdw_w[2] = {(const float*)d_in[6],  (const float*)d_in[11]};
    const float* q_w[2]    = {(const float*)d_in[7],  (const float*)d_in[12]};
    const float* qdw_w[2]  = {(const float*)d_in[8],  (const float*)d_in[13]};
    const float* po_w[2]   = {(const float*)d_in[9],  (const float*)d_in[14]};
    const float* mm_w[2]   = {(const float*)d_in[15], (const float*)d_in[17]};
    const float* mm_b[2]   = {(const float*)d_in[16], (const float*)d_in[18]};

    const size_t HPE = (size_t)BATCH*64*HW;     // elems per 64-ch plane
    u16* x1 = (u16*)d_ws;
    u16* y1 = x1 + HPE;
    u16* pool = y1 + HPE;                       // 6 planes P0..P5
    u16* P[6]; for (int i = 0; i < 6; i++) P[i] = pool + (size_t)i*HPE;
    float* attn_ws = (float*)(pool + 6*HPE);    // B*8*8*8 = 2048 floats

    size_t need = 8*HPE*2 + (size_t)2048*4;
    if (ws_size < need) return;

    ln_kernel<<<NPIX/256, 256, 0, stream>>>(x, ln_w, ln_b, x1);
    ln_kernel<<<NPIX/256, 256, 0, stream>>>(y, ln_w, ln_b, y1);

    float* outp = (float*)d_out;
    for (int br = 0; br < 2; br++){
        const u16*   in_kv  = br==0 ? x1 : y1;
        const u16*   in_q   = br==0 ? y1 : x1;
        const float* mod_in = br==0 ? x  : y;
        const float* resid  = br==0 ? y  : x;
        u16* KV  = P[0];   // P0+P1: [B,128,HW]
        u16* TKV = P[2];   // P2+P3 transient

        conv1x1_kernel<u16,64,128,false,false><<<NPIX/256, 256, 0, stream>>>(in_kv, kv_w[br], nullptr, TKV);
        dwconv_kernel<<<(BATCH*128*HW)/256, 256, 0, stream>>>(TKV, kvdw_w[br], KV, 128);
        conv1x1_kernel<u16,64,64,false,false><<<NPIX/256, 256, 0, stream>>>(in_q, q_w[br], nullptr, P[2]);
        dwconv_kernel<<<(BATCH*64*HW)/256, 256, 0, stream>>>(P[2], qdw_w[br], P[3], 64);
        // modulation: s = conv(lrelu(conv(mod_in, mw0, mb0)), mw1, mb1); t likewise with mw2/mw3
        conv1x1_kernel<float,64,64,true, true><<<NPIX/256, 256, 0, stream>>>(mod_in, mm_w[br],       mm_b[br],     P[2]);
        conv1x1_kernel<u16,  64,64,false,true><<<NPIX/256, 256, 0, stream>>>(P[2],   mm_w[br]+4096,  mm_b[br]+64,  P[4]);
        conv1x1_kernel<float,64,64,true, true><<<NPIX/256, 256, 0, stream>>>(mod_in, mm_w[br]+8192,  mm_b[br]+128, P[2]);
        conv1x1_kernel<u16,  64,64,false,true><<<NPIX/256, 256, 0, stream>>>(P[2],   mm_w[br]+12288, mm_b[br]+192, P[5]);
        vmod_kernel<<<(BATCH*64*HW)/256, 256, 0, stream>>>(KV, P[4], P[5]);
        attn_kernel<<<BATCH*8, 256, 0, stream>>>(P[3], KV, temp, attn_ws);
        final_kernel<<<NPIX/256, 256, 0, stream>>>(KV, attn_ws, po_w[br], resid, outp + (size_t)br*HPE);
    }
}

// Round 4
// 887.831 us; speedup vs baseline: 3.4815x; 3.4815x over previous
//
#include <hip/hip_runtime.h>
#include <hip/hip_bf16.h>

#define HW 65536
#define BATCH 4
#define NPIX (BATCH*HW)   // 262144 pixels

typedef unsigned short u16;
typedef unsigned int   u32;
typedef __attribute__((ext_vector_type(8))) short bh8;   // 8 bf16 (A/B frag, 4 VGPRs)
typedef __attribute__((ext_vector_type(4))) float f4;    // 4 f32 (C/D frag)

__device__ __forceinline__ float b2f(u16 u){
    u32 i = ((u32)u) << 16; float f; __builtin_memcpy(&f, &i, 4); return f;
}
__device__ __forceinline__ u16 f2b(float f){
    __hip_bfloat16 h = __float2bfloat16(f); u16 u; __builtin_memcpy(&u, &h, 2); return u;
}
__device__ __forceinline__ short ldb(const u16* p){ return (short)*p; }
__device__ __forceinline__ short ldb(const float* p){ return (short)f2b(*p); }

__device__ __forceinline__ f4 mfma16(bh8 a, bh8 b, f4 c){
    return __builtin_amdgcn_mfma_f32_16x16x32_bf16(a, b, c, 0, 0, 0);
}

// ---------------- weight conversion (f32 -> bf16 arena) ----------------
struct CvtJob { const float* src; u16* dst; int n; };
struct CvtJobs { CvtJob j[12]; };
__global__ void cvt_kernel(CvtJobs jobs){
    const CvtJob J = jobs.j[blockIdx.x];
    for (int i = threadIdx.x; i < J.n; i += 256) J.dst[i] = f2b(J.src[i]);
}
__global__ void zero_kernel(float* p, int n){
    int i = blockIdx.x*256 + threadIdx.x;
    if (i < n) p[i] = 0.f;
}

// ---------------- LayerNorm, 2 px/thread (f32 in -> bf16 out) ----------------
__global__ __launch_bounds__(256) void ln2_kernel(const float* __restrict__ x,
                                                  const float* __restrict__ w,
                                                  const float* __restrict__ bs,
                                                  u16* __restrict__ out){
    int gid = blockIdx.x*256 + threadIdx.x;          // NPIX/2 groups
    int b = gid >> 15;                               // 32768 groups per batch
    int p = (gid & 32767) << 1;
    const float* px = x + (size_t)b*64*HW + p;
    u16* po = out + (size_t)b*64*HW + p;
    float v0[64], v1[64]; float mu0 = 0.f, mu1 = 0.f;
    #pragma unroll
    for (int c = 0; c < 64; c++){
        float2 f = *(const float2*)(px + (size_t)c*HW);
        v0[c] = f.x; v1[c] = f.y; mu0 += f.x; mu1 += f.y;
    }
    mu0 *= (1.f/64.f); mu1 *= (1.f/64.f);
    float va0 = 0.f, va1 = 0.f;
    #pragma unroll
    for (int c = 0; c < 64; c++){
        float d0 = v0[c]-mu0, d1 = v1[c]-mu1; va0 = fmaf(d0,d0,va0); va1 = fmaf(d1,d1,va1);
    }
    float i0 = rsqrtf(va0*(1.f/64.f) + 1e-5f);
    float i1 = rsqrtf(va1*(1.f/64.f) + 1e-5f);
    #pragma unroll
    for (int c = 0; c < 64; c++){
        u32 pk = (u32)f2b((v0[c]-mu0)*i0*w[c] + bs[c])
               | ((u32)f2b((v1[c]-mu1)*i1*w[c] + bs[c]) << 16);
        *(u32*)(po + (size_t)c*HW) = pk;
    }
}

// ---------------- MFMA GEMM over pixels ----------------
// M = MT*16 out-channels, K = KT*32 in-channels. Input planes are [B][64][HW]
// (inHi used for k>=64). Weights WA: bf16 [M][KD] row-major, KD = DIAG2?64:K.
// EPI: 0 = store bf16 planes, 1 = +bias+lrelu, 2 = vmod (v = v*(s+1)+t on vP),
//      3 = final (+f32 resid, f32 store, per-batch Weff A-matrix)
template<int MT, int KT, bool DIAG2, int EPI, typename TB>
__global__ __launch_bounds__(256) void gemm_kernel(
        const TB* __restrict__ inLo, const TB* __restrict__ inHi,
        const u16* __restrict__ WA,
        const float* __restrict__ bias_lo, const float* __restrict__ bias_hi,
        u16* __restrict__ outLo, u16* __restrict__ outHi,
        u16* __restrict__ vP,
        const float* __restrict__ resid, float* __restrict__ outF){
    constexpr int KD = DIAG2 ? (KT/2)*32 : KT*32;   // arena row stride
    constexpr int KA = DIAG2 ? KT/2 : KT;           // stored k-steps per row
    int tile = blockIdx.x;                          // NPIX/128 tiles
    int w = threadIdx.x >> 6, lane = threadIdx.x & 63;
    int quad = lane >> 4, l16 = lane & 15;
    int b = tile >> 9;                              // 512 tiles per batch
    int ploc = ((tile & 511) << 7) + (w << 5) + l16;  // pixel within batch (+col)

    // A fragments from the bf16 weight arena (contiguous 16B per frag)
    bh8 a[MT][KA];
    const u16* wbase = (EPI == 3) ? (WA + b*4096) : WA;
    #pragma unroll
    for (int mi = 0; mi < MT; mi++){
        int row = mi*16 + l16;
        #pragma unroll
        for (int ks = 0; ks < KA; ks++)
            __builtin_memcpy(&a[mi][ks], wbase + row*KD + ks*32 + quad*8, 16);
    }
    f4 acc[MT][2];
    #pragma unroll
    for (int mi = 0; mi < MT; mi++){ acc[mi][0] = (f4){0.f,0.f,0.f,0.f}; acc[mi][1] = (f4){0.f,0.f,0.f,0.f}; }

    #pragma unroll
    for (int ks = 0; ks < KT; ks++){
        int kblk = ks*32 + quad*8;
        const TB* base = (kblk < 64) ? inLo : inHi;
        const TB* pp = base + ((size_t)b*64 + (kblk & 63))*HW + ploc;
        bh8 b0, b1;
        #pragma unroll
        for (int j = 0; j < 8; j++){
            b0[j] = ldb(pp + (size_t)j*HW);
            b1[j] = ldb(pp + (size_t)j*HW + 16);
        }
        #pragma unroll
        for (int mi = 0; mi < MT; mi++){
            if (!DIAG2 || (mi < MT/2 ? (ks < KT/2) : (ks >= KT/2))){
                int ksl = (DIAG2 && mi >= MT/2) ? ks - KT/2 : ks;
                acc[mi][0] = mfma16(a[mi][ksl], b0, acc[mi][0]);
                acc[mi][1] = mfma16(a[mi][ksl], b1, acc[mi][1]);
            }
        }
    }

    if constexpr (EPI == 2){
        // rows 0..63 = s (+bias_lo), rows 64..127 = t (+bias_hi); v' = v*(s+1)+t
        #pragma unroll
        for (int mi = 0; mi < MT/2; mi++)
        #pragma unroll
        for (int nn = 0; nn < 2; nn++)
        #pragma unroll
        for (int r = 0; r < 4; r++){
            int o = mi*16 + quad*4 + r;
            size_t pidx = ((size_t)b*64 + o)*HW + ploc + nn*16;
            float s = acc[mi][nn][r] + bias_lo[o];
            float t = acc[mi+MT/2][nn][r] + bias_hi[o];
            float v = b2f(vP[pidx]);
            vP[pidx] = f2b(v*(s+1.f)+t);
        }
    } else {
        #pragma unroll
        for (int mi = 0; mi < MT; mi++)
        #pragma unroll
        for (int nn = 0; nn < 2; nn++)
        #pragma unroll
        for (int r = 0; r < 4; r++){
            int o = mi*16 + quad*4 + r;
            size_t pidx = ((size_t)b*64 + (o & 63))*HW + ploc + nn*16;
            float va = acc[mi][nn][r];
            if constexpr (EPI == 3){
                outF[pidx] = va + resid[pidx];
            } else {
                if constexpr (EPI == 1){
                    va += (o < 64) ? bias_lo[o] : bias_hi[o-64];
                    va = va > 0.f ? va : 0.1f*va;
                }
                u16* dst = (o < 64) ? outLo : outHi;
                dst[pidx] = f2b(va);
            }
        }
    }
}

// ---------------- depthwise 3x3, 8 px/thread, vectorized ----------------
__global__ __launch_bounds__(256) void dw8_kernel(const u16* __restrict__ in,
                                                  const float* __restrict__ wdw, int choff,
                                                  u16* __restrict__ out){
    int gid = blockIdx.x*256 + threadIdx.x;     // B*64*8192 groups
    int bc = gid >> 13;
    int n8 = gid & 8191;
    int h = n8 >> 5, c8 = (n8 & 31) << 3;
    const float* wc = wdw + ((size_t)((bc & 63) + choff))*9;
    const u16* p = in + (size_t)bc*HW;
    float row[3][10];
    #pragma unroll
    for (int r = 0; r < 3; r++){
        int hh = h - 1 + r;
        bool ok = (unsigned)hh < 256u;
        const u16* pr = p + hh*256 + c8;
        if (ok){
            uint4 m = *(const uint4*)pr;          // 8 bf16
            row[r][1] = b2f((u16)m.x); row[r][2] = b2f((u16)(m.x>>16));
            row[r][3] = b2f((u16)m.y); row[r][4] = b2f((u16)(m.y>>16));
            row[r][5] = b2f((u16)m.z); row[r][6] = b2f((u16)(m.z>>16));
            row[r][7] = b2f((u16)m.w); row[r][8] = b2f((u16)(m.w>>16));
            row[r][0] = (c8 > 0)   ? b2f(pr[-1]) : 0.f;
            row[r][9] = (c8 < 248) ? b2f(pr[8])  : 0.f;
        } else {
            #pragma unroll
            for (int j = 0; j < 10; j++) row[r][j] = 0.f;
        }
    }
    float o[8];
    #pragma unroll
    for (int i = 0; i < 8; i++){
        float a = 0.f;
        #pragma unroll
        for (int r = 0; r < 3; r++){
            a = fmaf(wc[r*3+0], row[r][i],   a);
            a = fmaf(wc[r*3+1], row[r][i+1], a);
            a = fmaf(wc[r*3+2], row[r][i+2], a);
        }
        o[i] = a;
    }
    uint4 st;
    st.x = (u32)f2b(o[0]) | ((u32)f2b(o[1])<<16);
    st.y = (u32)f2b(o[2]) | ((u32)f2b(o[3])<<16);
    st.z = (u32)f2b(o[4]) | ((u32)f2b(o[5])<<16);
    st.w = (u32)f2b(o[6]) | ((u32)f2b(o[7])<<16);
    *(uint4*)(out + (size_t)bc*HW + h*256 + c8) = st;
}

// ---------------- attention partial sums (Gram + norms), atomic ----------------
#define NSL 64
__global__ __launch_bounds__(256) void attn_part_kernel(const u16* __restrict__ q,
                                                        const u16* __restrict__ k,
                                                        float* __restrict__ sums){
    int blk = blockIdx.x;            // B*8*NSL
    int sl = blk & (NSL-1);
    int bh = blk >> 6;               // b*8+h
    int b = bh >> 3, h = bh & 7;
    const u16* qp = q + ((size_t)b*64 + h*8)*HW + sl*(HW/NSL);
    const u16* kp = k + ((size_t)b*64 + h*8)*HW + sl*(HW/NSL);
    float acc[80];
    #pragma unroll
    for (int i = 0; i < 80; i++) acc[i] = 0.f;
    for (int n = threadIdx.x; n < HW/NSL; n += 256){
        float qv[8], kw[8];
        #pragma unroll
        for (int i = 0; i < 8; i++){
            qv[i] = b2f(qp[(size_t)i*HW + n]);
            kw[i] = b2f(kp[(size_t)i*HW + n]);
        }
        #pragma unroll
        for (int i = 0; i < 8; i++){
            acc[64+i] = fmaf(qv[i], qv[i], acc[64+i]);
            acc[72+i] = fmaf(kw[i], kw[i], acc[72+i]);
            #pragma unroll
            for (int j = 0; j < 8; j++) acc[i*8+j] = fmaf(qv[i], kw[j], acc[i*8+j]);
        }
    }
    __shared__ float sred[4][80];
    int lane = threadIdx.x & 63, wv = threadIdx.x >> 6;
    #pragma unroll
    for (int t = 0; t < 80; t++){
        float r = acc[t];
        r += __shfl_down(r, 32); r += __shfl_down(r, 16); r += __shfl_down(r, 8);
        r += __shfl_down(r, 4);  r += __shfl_down(r, 2);  r += __shfl_down(r, 1);
        if (lane == 0) sred[wv][t] = r;
    }
    __syncthreads();
    if (threadIdx.x < 80){
        int t = threadIdx.x;
        atomicAdd(&sums[bh*80 + t], sred[0][t]+sred[1][t]+sred[2][t]+sred[3][t]);
    }
}

// ---------------- softmax + Weff = po ∘ attn (per batch) ----------------
__global__ __launch_bounds__(64) void weff_kernel(const float* __restrict__ sums,
                                                  const float* __restrict__ temp,
                                                  const float* __restrict__ po,
                                                  u16* __restrict__ weff){
    int b = blockIdx.x;
    __shared__ float at[8][8][8];
    int t = threadIdx.x;          // 0..63
    {
        int h = t >> 3, i = t & 7;
        const float* f = sums + (b*8 + h)*80;
        float iq = 1.f / fmaxf(sqrtf(f[64+i]), 1e-12f);
        float tv = temp[h];
        float row[8]; float m = -1e30f;
        #pragma unroll
        for (int j = 0; j < 8; j++){
            float ik = 1.f / fmaxf(sqrtf(f[72+j]), 1e-12f);
            row[j] = f[i*8+j]*iq*ik*tv;
            m = fmaxf(m, row[j]);
        }
        float s = 0.f;
        #pragma unroll
        for (int j = 0; j < 8; j++){ row[j] = expf(row[j]-m); s += row[j]; }
        float rs = 1.f/s;
        #pragma unroll
        for (int j = 0; j < 8; j++) at[h][i][j] = row[j]*rs;
    }
    __syncthreads();
    int o = t;
    for (int g = 0; g < 64; g++){
        int h = g >> 3, j = g & 7;
        float wv = 0.f;
        #pragma unroll
        for (int i = 0; i < 8; i++) wv = fmaf(po[o*64 + h*8 + i], at[h][i][j], wv);
        weff[b*4096 + o*64 + g] = f2b(wv);
    }
}

extern "C" void kernel_launch(void* const* d_in, const int* in_sizes, int n_in,
                              void* d_out, int out_size, void* d_ws, size_t ws_size,
                              hipStream_t stream){
    const float* x    = (const float*)d_in[0];
    const float* y    = (const float*)d_in[1];
    const float* ln_w = (const float*)d_in[2];
    const float* ln_b = (const float*)d_in[3];
    const float* temp = (const float*)d_in[4];
    const float* kv_w[2]   = {(const float*)d_in[5],  (const float*)d_in[10]};
    const float* kvdw_w[2] = {(const float*)d_in[6],  (const float*)d_in[11]};
    const float* q_w[2]    = {(const float*)d_in[7],  (const float*)d_in[12]};
    const float* qdw_w[2]  = {(const float*)d_in[8],  (const float*)d_in[13]};
    const float* po_w[2]   = {(const float*)d_in[9],  (const float*)d_in[14]};
    const float* mm_w[2]   = {(const float*)d_in[15], (const float*)d_in[17]};
    const float* mm_b[2]   = {(const float*)d_in[16], (const float*)d_in[18]};

    const size_t HPE = (size_t)BATCH*64*HW;   // elems per 64-ch plane
    u16* PL = (u16*)d_ws;                     // 7 planes
    u16* x1 = PL;            u16* y1 = PL +   HPE;
    u16* A  = PL + 2*HPE;    u16* Bp = PL + 3*HPE;
    u16* C  = PL + 4*HPE;    u16* D  = PL + 5*HPE;
    u16* G  = PL + 6*HPE;
    float* sums = (float*)(PL + 7*HPE);       // 2 * 2560 f32
    u16* warena = (u16*)(sums + 5120);
    // arena offsets (u16): kv0 0, kv1 8192, q0 16384, q1 20480,
    //                      ma0 24576, mb0 32768, ma1 40960, mb1 49152, weff 57344
    const int WKV[2] = {0, 8192}, WQ[2] = {16384, 20480};
    const int WMA[2] = {24576, 40960}, WMB[2] = {32768, 49152};
    const int WEFF = 57344;

    size_t need = 7*HPE*2 + 5120*4 + 73728*2;
    if (ws_size < need) return;

    CvtJobs jobs{}; int nj = 0;
    auto add = [&](const float* s, u16* d, int n){ jobs.j[nj] = {s, d, n}; nj++; };
    for (int br = 0; br < 2; br++){
        add(kv_w[br],        warena + WKV[br],        8192);
        add(q_w[br],         warena + WQ[br],         4096);
        add(mm_w[br],        warena + WMA[br],        4096);  // W0 -> rows 0-63
        add(mm_w[br]+8192,   warena + WMA[br] + 4096, 4096);  // W2 -> rows 64-127
        add(mm_w[br]+4096,   warena + WMB[br],        4096);  // W1 -> rows 0-63
        add(mm_w[br]+12288,  warena + WMB[br] + 4096, 4096);  // W3 -> rows 64-127
    }
    cvt_kernel<<<nj, 256, 0, stream>>>(jobs);
    zero_kernel<<<20, 256, 0, stream>>>(sums, 5120);

    ln2_kernel<<<NPIX/512, 256, 0, stream>>>(x, ln_w, ln_b, x1);
    ln2_kernel<<<NPIX/512, 256, 0, stream>>>(y, ln_w, ln_b, y1);

    float* outp = (float*)d_out;
    const int GT = NPIX/128;     // 2048 gemm tiles
    const int GD = BATCH*64*HW/2048;  // 8192 dw blocks per 64-ch plane
    for (int br = 0; br < 2; br++){
        const u16*   in_kv  = br==0 ? x1 : y1;
        const u16*   in_q   = br==0 ? y1 : x1;
        const float* mod_in = br==0 ? x  : y;
        const float* resid  = br==0 ? y  : x;
        float* sb = sums + br*2560;

        // kv conv (M=128) -> A(k-pre), B(v-pre)
        gemm_kernel<8,2,false,0,u16><<<GT, 256, 0, stream>>>(
            in_kv, in_kv, warena + WKV[br], nullptr, nullptr, A, Bp, nullptr, nullptr, nullptr);
        // depthwise on both halves: A->C (k), B->D (v)
        dw8_kernel<<<GD, 256, 0, stream>>>(A,  kvdw_w[br], 0,  C);
        dw8_kernel<<<GD, 256, 0, stream>>>(Bp, kvdw_w[br], 64, D);
        // q conv (M=64) -> A, then depthwise A->B
        gemm_kernel<4,2,false,0,u16><<<GT, 256, 0, stream>>>(
            in_q, in_q, warena + WQ[br], nullptr, nullptr, A, nullptr, nullptr, nullptr, nullptr);
        dw8_kernel<<<GD, 256, 0, stream>>>(A, qdw_w[br], 0, Bp);
        // modulation conv-a (stacked M=128, f32 input) -> A (m1), G (m2), bias+lrelu
        gemm_kernel<8,2,false,1,float><<<GT, 256, 0, stream>>>(
            mod_in, mod_in, warena + WMA[br], mm_b[br], mm_b[br]+128, A, G, nullptr, nullptr, nullptr);
        // modulation conv-b (block-diag M=128,K=128) + fused vmod on D
        gemm_kernel<8,4,true,2,u16><<<GT, 256, 0, stream>>>(
            A, G, warena + WMB[br], mm_b[br]+64, mm_b[br]+192, nullptr, nullptr, D, nullptr, nullptr);
        // attention stats (q = B, k = C) -> sums, then softmax + Weff
        attn_part_kernel<<<BATCH*8*NSL, 256, 0, stream>>>(Bp, C, sb);
        weff_kernel<<<BATCH, 64, 0, stream>>>(sb, temp, po_w[br], warena + WEFF);
        // final: Weff x V + resid -> f32 out
        gemm_kernel<4,2,false,3,u16><<<GT, 256, 0, stream>>>(
            D, D, warena + WEFF, nullptr, nullptr, nullptr, nullptr, nullptr,
            resid, outp + (size_t)br*HPE);
    }
}